// Round 2
// baseline (575.740 us; speedup 1.0000x reference)
//
#include <hip/hip_runtime.h>
#include <hip/hip_bf16.h>

#define DIM 192
#define HEADS 6
#define HD 32
#define NTOK 64
#define BATCH 2048
#define CPBH 512
#define TBL 343
#define NW 64

typedef unsigned int u32;
typedef __attribute__((ext_vector_type(8))) short b16x8;
typedef __attribute__((ext_vector_type(4))) float f32x4;

__device__ __forceinline__ unsigned short f2bf(float f) {
  union { __hip_bfloat16 h; unsigned short s; } cv;
  cv.h = __float2bfloat16(f);
  return cv.s;
}
__device__ __forceinline__ u32 pack2(float a, float b) {
  return (u32)f2bf(a) | ((u32)f2bf(b) << 16);
}
union FragU { u32 u[4]; b16x8 s; uint4 q; };

__device__ __forceinline__ b16x8 ld_frag_g(const u32* p) {
  FragU f; f.q = *(const uint4*)p; return f.s;
}

// ---------- merged prep: CPB MLP (blocks 0..87) + weight cvt (blocks 88..375) ----------
__global__ __launch_bounds__(256) void k_prep(
    const float* __restrict__ rpb, const float* __restrict__ w1,
    const float* __restrict__ b1, const float* __restrict__ w2,
    float* __restrict__ tab,
    const float* __restrict__ qkvw, const float* __restrict__ pw,
    u32* __restrict__ wq, u32* __restrict__ wp) {
  const int tid = threadIdx.x;
  if (blockIdx.x < 88) {
    // CPB MLP: one wave per table row
    int t = blockIdx.x * 4 + (tid >> 6);
    int lane = tid & 63;
    if (t >= TBL) return;
    float r0 = rpb[t*3], r1 = rpb[t*3+1], r2 = rpb[t*3+2];
    float a[HEADS];
    #pragma unroll
    for (int h = 0; h < HEADS; ++h) a[h] = 0.f;
    #pragma unroll
    for (int kk = 0; kk < 8; ++kk) {
      int k = lane * 8 + kk;
      float hv = fmaf(r0, w1[k*3], fmaf(r1, w1[k*3+1], fmaf(r2, w1[k*3+2], b1[k])));
      hv = fmaxf(hv, 0.f);
      #pragma unroll
      for (int h = 0; h < HEADS; ++h) a[h] = fmaf(hv, w2[h*CPBH + k], a[h]);
    }
    #pragma unroll
    for (int h = 0; h < HEADS; ++h) {
      a[h] += __shfl_xor(a[h], 1);  a[h] += __shfl_xor(a[h], 2);
      a[h] += __shfl_xor(a[h], 4);  a[h] += __shfl_xor(a[h], 8);
      a[h] += __shfl_xor(a[h], 16); a[h] += __shfl_xor(a[h], 32);
    }
    if (lane == 0) {
      #pragma unroll
      for (int h = 0; h < HEADS; ++h) tab[t*HEADS + h] = a[h];
    }
    return;
  }
  // weight conversion. qkv weights row-PERMUTED so the QKV MFMA output layout
  // directly equals the attention A-fragment layout:
  //   slot (head h, tensor s, half hf, pos p) <- orig dim d = (p>>2)*8 + hf*4 + (p&3)
  int i = (blockIdx.x - 88) * 256 + tid;
  if (i < 55296) {
    int R = i / 96, c = i % 96;
    int h  = R / 96;
    int t  = R - h * 96;
    int s3 = t >> 5;
    int u  = t & 31;
    int hf = (u >> 4) & 1;
    int p  = u & 15;
    int d  = ((p >> 2) << 3) + (hf << 2) + (p & 3);
    int orig = s3 * 192 + h * 32 + d;
    wq[i] = pack2(qkvw[orig*192 + 2*c], qkvw[orig*192 + 2*c + 1]);
  } else if (i < 55296 + 18432) {
    int j = i - 55296;
    wp[j] = pack2(pw[2*j], pw[2*j+1]);
  }
}

// ---------- bias+mask table, TRANSPOSED layout: (nW, H, col, row) fp32 ----------
// lets the fused kernel load bias as float4 over the query-row quad (qd*4+r)
__global__ void k_bm(const float* __restrict__ tab, const int* __restrict__ ridx,
                     const float* __restrict__ mask, float* __restrict__ bm) {
  int idx = blockIdx.x * blockDim.x + threadIdx.x;
  if (idx >= NW * HEADS * 4096) return;
  int row = idx & 63;            // query index i
  int col = (idx >> 6) & 63;     // key index j
  int h = (idx >> 12) % HEADS;
  int nw = idx / (HEADS * 4096);
  int ij = row * 64 + col;       // table index is (i,j) row-major
  float v = tab[ridx[ij] * HEADS + h];
  bm[idx] = 16.f / (1.f + __expf(-v)) + mask[nw * 4096 + ij];
}

// ---------- fully fused: QKV + cosine attention + projection ----------
// one block per window; wave = head. LDS regions union'd by lifetime:
//   rA: xl (phase 2) / pbt (phase 3)          25,856 B
//   rB: vTL (phase 2 -> vfr regs) / aol (3-4) 26,880 B
// total 52,736 B -> 3 blocks/CU (was 66,176 -> 2)
union RegA { u32 xl[NTOK * 101]; u32 pbt[HEADS][16 * 35]; };
union RegB { u32 vTL[HEADS][32 * 35]; u32 aol[NTOK * 99]; };

__global__ __launch_bounds__(384, 5) void k_fused(
    const float* __restrict__ x, const u32* __restrict__ wq,
    const float* __restrict__ qkvb, const float* __restrict__ bm,
    const float* __restrict__ ls, const u32* __restrict__ wp,
    const float* __restrict__ pb, float* __restrict__ out) {
  __shared__ RegA rA;
  __shared__ RegB rB;

  const int tid = threadIdx.x;
  const int b = blockIdx.x;
  const int h = tid >> 6;               // wave = head
  const int lane = tid & 63;
  const int m = lane & 15, qd = lane >> 4;

  // ---- phase 1: stage x as bf16 ----
  {
    const float4* xg = (const float4*)(x + (size_t)b * (NTOK * DIM));
    for (int i = tid; i < (NTOK * DIM) / 4; i += 384) {
      float4 v = xg[i];
      int flat = i * 4, tok = flat / DIM, k = flat % DIM;
      rA.xl[tok*101 + k/2]     = pack2(v.x, v.y);
      rA.xl[tok*101 + k/2 + 1] = pack2(v.z, v.w);
    }
  }
  __syncthreads();

  // ---- phase 2: QKV for own head; q,k -> registers, v -> vTL ----
  b16x8 qfv[4], kfv[4];
  #pragma unroll
  for (int s3 = 0; s3 < 3; ++s3) {
    b16x8 afr[2][6];
    float bv[2][4];
    #pragma unroll
    for (int hf = 0; hf < 2; ++hf) {
      const u32* wrow = wq + (size_t)(((h*3 + s3)*2 + hf)*16 + m) * 96;
      #pragma unroll
      for (int ks = 0; ks < 6; ++ks) afr[hf][ks] = ld_frag_g(wrow + ks*16 + qd*4);
      #pragma unroll
      for (int r = 0; r < 4; ++r) bv[hf][r] = qkvb[s3*192 + h*32 + qd*8 + hf*4 + r];
    }
    #pragma unroll
    for (int t = 0; t < 4; ++t) {
      f32x4 a0 = {0.f,0.f,0.f,0.f}, a1 = {0.f,0.f,0.f,0.f};
      #pragma unroll
      for (int ks = 0; ks < 6; ++ks) {
        b16x8 bfr = *(const b16x8*)(&rA.xl[(t*16 + m)*101 + ks*16 + qd*4]);
        a0 = __builtin_amdgcn_mfma_f32_16x16x32_bf16(afr[0][ks], bfr, a0, 0,0,0);
        a1 = __builtin_amdgcn_mfma_f32_16x16x32_bf16(afr[1][ks], bfr, a1, 0,0,0);
      }
      #pragma unroll
      for (int r = 0; r < 4; ++r) { a0[r] += bv[0][r]; a1[r] += bv[1][r]; }
      if (s3 < 2) {
        float ss = 0.f;
        #pragma unroll
        for (int r = 0; r < 4; ++r) ss = fmaf(a0[r],a0[r], fmaf(a1[r],a1[r], ss));
        ss += __shfl_xor(ss, 16);
        ss += __shfl_xor(ss, 32);
        float inv = 1.f / fmaxf(sqrtf(ss), 1e-12f);
        FragU tf;
        tf.u[0] = pack2(a0[0]*inv, a0[1]*inv);
        tf.u[1] = pack2(a0[2]*inv, a0[3]*inv);
        tf.u[2] = pack2(a1[0]*inv, a1[1]*inv);
        tf.u[3] = pack2(a1[2]*inv, a1[3]*inv);
        if (s3 == 0) qfv[t] = tf.s; else kfv[t] = tf.s;
      } else {
        float v8[8];
        #pragma unroll
        for (int r = 0; r < 4; ++r) { v8[r] = a0[r]; v8[4+r] = a1[r]; }
        #pragma unroll
        for (int e = 0; e < 8; ++e) {
          float pn = __shfl_xor(v8[e], 1);
          if ((m & 1) == 0) {
            int d = qd*8 + (e>>2)*4 + (e&3);
            rB.vTL[h][d*35 + t*8 + (m>>1)] = pack2(v8[e], pn);
          }
        }
      }
    }
  }
  __syncthreads();   // xl dead; vTL complete

  // ---- load V^T fragments into registers, then free vTL for aol ----
  b16x8 vfr[2][2];
  #pragma unroll
  for (int nt = 0; nt < 2; ++nt)
    #pragma unroll
    for (int ks = 0; ks < 2; ++ks)
      vfr[nt][ks] = *(const b16x8*)(&rB.vTL[h][(nt*16 + m)*35 + ks*16 + qd*4]);
  __syncthreads();   // vTL dead -> aol may be written; xl dead -> pbt may be written

  // ---- phase 3: attention (per-head wave), merged softmax+PV per q-tile ----
  const float sc = __expf(fminf(ls[h], 4.60517019f));
  const float* bmp = bm + ((size_t)(b & 63) * HEADS + h) * 4096;  // (col, row) layout
  u32* pbw = rA.pbt[h];
  #pragma unroll
  for (int mt = 0; mt < 4; ++mt) {
    f32x4 s4[4];
    #pragma unroll
    for (int ct = 0; ct < 4; ++ct) {
      f32x4 z = {0.f,0.f,0.f,0.f};
      s4[ct] = __builtin_amdgcn_mfma_f32_16x16x32_bf16(qfv[mt], kfv[ct], z, 0,0,0);
    }
    #pragma unroll
    for (int ct = 0; ct < 4; ++ct) {
      float4 b4 = *(const float4*)(bmp + (ct*16 + m)*64 + mt*16 + qd*4);
      s4[ct][0] = fmaf(s4[ct][0], sc, b4.x);
      s4[ct][1] = fmaf(s4[ct][1], sc, b4.y);
      s4[ct][2] = fmaf(s4[ct][2], sc, b4.z);
      s4[ct][3] = fmaf(s4[ct][3], sc, b4.w);
    }
    float rinv[4];
    #pragma unroll
    for (int r = 0; r < 4; ++r) {
      float mm = s4[0][r];
      #pragma unroll
      for (int ct = 1; ct < 4; ++ct) mm = fmaxf(mm, s4[ct][r]);
      mm = fmaxf(mm, __shfl_xor(mm, 1)); mm = fmaxf(mm, __shfl_xor(mm, 2));
      mm = fmaxf(mm, __shfl_xor(mm, 4)); mm = fmaxf(mm, __shfl_xor(mm, 8));
      float l = 0.f;
      #pragma unroll
      for (int ct = 0; ct < 4; ++ct) { s4[ct][r] = __expf(s4[ct][r] - mm); l += s4[ct][r]; }
      l += __shfl_xor(l, 1); l += __shfl_xor(l, 2);
      l += __shfl_xor(l, 4); l += __shfl_xor(l, 8);
      rinv[r] = 1.f / l;
      int rloc = qd*4 + r;
      #pragma unroll
      for (int ct = 0; ct < 4; ++ct) {
        float pv = s4[ct][r];
        float pn = __shfl_xor(pv, 1);
        if ((m & 1) == 0) pbw[rloc*35 + ct*8 + (m >> 1)] = pack2(pv, pn);
      }
    }
    b16x8 pa0 = *(const b16x8*)(&pbw[m*35 + qd*4]);
    b16x8 pa1 = *(const b16x8*)(&pbw[m*35 + 16 + qd*4]);
    #pragma unroll
    for (int nt = 0; nt < 2; ++nt) {
      f32x4 o = {0.f,0.f,0.f,0.f};
      o = __builtin_amdgcn_mfma_f32_16x16x32_bf16(pa0, vfr[nt][0], o, 0,0,0);
      o = __builtin_amdgcn_mfma_f32_16x16x32_bf16(pa1, vfr[nt][1], o, 0,0,0);
      #pragma unroll
      for (int r = 0; r < 4; ++r) {
        float val = o[r] * rinv[r];
        float pn = __shfl_xor(val, 1);
        if ((m & 1) == 0)
          rB.aol[(mt*16 + qd*4 + r)*99 + h*16 + nt*8 + (m >> 1)] = pack2(val, pn);
      }
    }
  }
  __syncthreads();

  // ---- phase 4: projection; wave wv handles output cols wv*32..wv*32+31 ----
  const int wv = h;
  b16x8 pfr[2][6];
  float pbv[2][4];
  #pragma unroll
  for (int jj = 0; jj < 2; ++jj) {
    const u32* wrow = wp + (size_t)((wv*2 + jj)*16 + m) * 96;
    #pragma unroll
    for (int ks = 0; ks < 6; ++ks) pfr[jj][ks] = ld_frag_g(wrow + ks*16 + qd*4);
    #pragma unroll
    for (int r = 0; r < 4; ++r) pbv[jj][r] = pb[(wv*2 + jj)*16 + qd*4 + r];
  }
  #pragma unroll 1
  for (int t = 0; t < 4; ++t) {
    f32x4 acc0 = {0.f,0.f,0.f,0.f}, acc1 = {0.f,0.f,0.f,0.f};
    #pragma unroll
    for (int ks = 0; ks < 6; ++ks) {
      b16x8 bfr = *(const b16x8*)(&rB.aol[(t*16 + m)*99 + ks*16 + qd*4]);
      acc0 = __builtin_amdgcn_mfma_f32_16x16x32_bf16(pfr[0][ks], bfr, acc0, 0,0,0);
      acc1 = __builtin_amdgcn_mfma_f32_16x16x32_bf16(pfr[1][ks], bfr, acc1, 0,0,0);
    }
    float* op = out + ((size_t)b*64 + t*16 + m) * DIM;
    *(float4*)(op + (wv*2+0)*16 + qd*4) =
        make_float4(acc0[0]+pbv[0][0], acc0[1]+pbv[0][1], acc0[2]+pbv[0][2], acc0[3]+pbv[0][3]);
    *(float4*)(op + (wv*2+1)*16 + qd*4) =
        make_float4(acc1[0]+pbv[1][0], acc1[1]+pbv[1][1], acc1[2]+pbv[1][2], acc1[3]+pbv[1][3]);
  }
}

extern "C" void kernel_launch(void* const* d_in, const int* in_sizes, int n_in,
                              void* d_out, int out_size, void* d_ws, size_t ws_size,
                              hipStream_t stream) {
  const float* x    = (const float*)d_in[0];
  const float* mask = (const float*)d_in[1];
  const float* rpb  = (const float*)d_in[2];
  const int*   ridx = (const int*)d_in[3];
  const float* w1   = (const float*)d_in[4];
  const float* b1   = (const float*)d_in[5];
  const float* w2   = (const float*)d_in[6];
  const float* qkvw = (const float*)d_in[7];
  const float* qkvb = (const float*)d_in[8];
  const float* pw   = (const float*)d_in[9];
  const float* pb   = (const float*)d_in[10];
  const float* ls   = (const float*)d_in[11];
  float* out = (float*)d_out;

  char* ws = (char*)d_ws;
  float* btab = (float*)(ws);                       // 16 KB slot
  float* bm   = (float*)(ws + 16384);               // 6,291,456 B
  u32* wq = (u32*)(ws + 16384 + 6291456);           // 221,184 B
  u32* wp = (u32*)(ws + 16384 + 6291456 + 221184);  // 73,728 B

  k_prep<<<376, 256, 0, stream>>>(rpb, w1, b1, w2, btab, qkvw, pw, wq, wp);
  k_bm<<<(NW * HEADS * 4096 + 255) / 256, 256, 0, stream>>>(btab, ridx, mask, bm);
  k_fused<<<BATCH, 384, 0, stream>>>(x, wq, qkvb, bm, ls, wp, pb, out);
}

// Round 3
// 445.980 us; speedup vs baseline: 1.2910x; 1.2910x over previous
//
#include <hip/hip_runtime.h>
#include <hip/hip_bf16.h>

#define DIM 192
#define HEADS 6
#define HD 32
#define NTOK 64
#define BATCH 2048
#define CPBH 512
#define TBL 343
#define NW 64

typedef unsigned int u32;
typedef __attribute__((ext_vector_type(8))) short b16x8;
typedef __attribute__((ext_vector_type(4))) float f32x4;

__device__ __forceinline__ unsigned short f2bf(float f) {
  union { __hip_bfloat16 h; unsigned short s; } cv;
  cv.h = __float2bfloat16(f);
  return cv.s;
}
__device__ __forceinline__ u32 pack2(float a, float b) {
  return (u32)f2bf(a) | ((u32)f2bf(b) << 16);
}
union FragU { u32 u[4]; b16x8 s; uint4 q; };

__device__ __forceinline__ b16x8 ld_frag_g(const u32* p) {
  FragU f; f.q = *(const uint4*)p; return f.s;
}

// ---------- merged prep: CPB MLP (blocks 0..87) + weight cvt (blocks 88..375) ----------
__global__ __launch_bounds__(256) void k_prep(
    const float* __restrict__ rpb, const float* __restrict__ w1,
    const float* __restrict__ b1, const float* __restrict__ w2,
    float* __restrict__ tab,
    const float* __restrict__ qkvw, const float* __restrict__ pw,
    u32* __restrict__ wq, u32* __restrict__ wp) {
  const int tid = threadIdx.x;
  if (blockIdx.x < 88) {
    // CPB MLP: one wave per table row
    int t = blockIdx.x * 4 + (tid >> 6);
    int lane = tid & 63;
    if (t >= TBL) return;
    float r0 = rpb[t*3], r1 = rpb[t*3+1], r2 = rpb[t*3+2];
    float a[HEADS];
    #pragma unroll
    for (int h = 0; h < HEADS; ++h) a[h] = 0.f;
    #pragma unroll
    for (int kk = 0; kk < 8; ++kk) {
      int k = lane * 8 + kk;
      float hv = fmaf(r0, w1[k*3], fmaf(r1, w1[k*3+1], fmaf(r2, w1[k*3+2], b1[k])));
      hv = fmaxf(hv, 0.f);
      #pragma unroll
      for (int h = 0; h < HEADS; ++h) a[h] = fmaf(hv, w2[h*CPBH + k], a[h]);
    }
    #pragma unroll
    for (int h = 0; h < HEADS; ++h) {
      a[h] += __shfl_xor(a[h], 1);  a[h] += __shfl_xor(a[h], 2);
      a[h] += __shfl_xor(a[h], 4);  a[h] += __shfl_xor(a[h], 8);
      a[h] += __shfl_xor(a[h], 16); a[h] += __shfl_xor(a[h], 32);
    }
    if (lane == 0) {
      #pragma unroll
      for (int h = 0; h < HEADS; ++h) tab[t*HEADS + h] = a[h];
    }
    return;
  }
  // weight conversion. qkv weights row-PERMUTED so the QKV MFMA output layout
  // directly equals the attention A-fragment layout:
  //   slot (head h, tensor s, half hf, pos p) <- orig dim d = (p>>2)*8 + hf*4 + (p&3)
  int i = (blockIdx.x - 88) * 256 + tid;
  if (i < 55296) {
    int R = i / 96, c = i % 96;
    int h  = R / 96;
    int t  = R - h * 96;
    int s3 = t >> 5;
    int u  = t & 31;
    int hf = (u >> 4) & 1;
    int p  = u & 15;
    int d  = ((p >> 2) << 3) + (hf << 2) + (p & 3);
    int orig = s3 * 192 + h * 32 + d;
    wq[i] = pack2(qkvw[orig*192 + 2*c], qkvw[orig*192 + 2*c + 1]);
  } else if (i < 55296 + 18432) {
    int j = i - 55296;
    wp[j] = pack2(pw[2*j], pw[2*j+1]);
  }
}

// ---------- bias+mask table, TRANSPOSED layout: (nW, H, col, row) fp32 ----------
// lets the fused kernel load bias as float4 over the query-row quad (qd*4+r)
__global__ void k_bm(const float* __restrict__ tab, const int* __restrict__ ridx,
                     const float* __restrict__ mask, float* __restrict__ bm) {
  int idx = blockIdx.x * blockDim.x + threadIdx.x;
  if (idx >= NW * HEADS * 4096) return;
  int row = idx & 63;            // query index i
  int col = (idx >> 6) & 63;     // key index j
  int h = (idx >> 12) % HEADS;
  int nw = idx / (HEADS * 4096);
  int ij = row * 64 + col;       // table index is (i,j) row-major
  float v = tab[ridx[ij] * HEADS + h];
  bm[idx] = 16.f / (1.f + __expf(-v)) + mask[nw * 4096 + ij];
}

// ---------- fully fused: QKV + cosine attention + projection ----------
// one block per window; wave = head. LDS regions union'd by lifetime:
//   rA: xl (phase 2) / pbt (phase 3)          25,856 B
//   rB: vTL (phase 2 -> vfr regs) / aol (3-4) 26,880 B
// total 52,736 B -> 3 blocks/CU.
// NOTE: __launch_bounds__(384,3): R2's (384,5) squeezed VGPR to 48 and
// caused ~850 MB/dispatch of spill traffic. (384,3) -> 84 VGPR, no spill,
// and 84 <= 102 so registers don't cap the 3-block LDS occupancy.
union RegA { u32 xl[NTOK * 101]; u32 pbt[HEADS][16 * 35]; };
union RegB { u32 vTL[HEADS][32 * 35]; u32 aol[NTOK * 99]; };

__global__ __launch_bounds__(384, 3) void k_fused(
    const float* __restrict__ x, const u32* __restrict__ wq,
    const float* __restrict__ qkvb, const float* __restrict__ bm,
    const float* __restrict__ ls, const u32* __restrict__ wp,
    const float* __restrict__ pb, float* __restrict__ out) {
  __shared__ RegA rA;
  __shared__ RegB rB;

  const int tid = threadIdx.x;
  const int b = blockIdx.x;
  const int h = tid >> 6;               // wave = head
  const int lane = tid & 63;
  const int m = lane & 15, qd = lane >> 4;

  // ---- phase 1: stage x as bf16 ----
  {
    const float4* xg = (const float4*)(x + (size_t)b * (NTOK * DIM));
    for (int i = tid; i < (NTOK * DIM) / 4; i += 384) {
      float4 v = xg[i];
      int flat = i * 4, tok = flat / DIM, k = flat % DIM;
      rA.xl[tok*101 + k/2]     = pack2(v.x, v.y);
      rA.xl[tok*101 + k/2 + 1] = pack2(v.z, v.w);
    }
  }
  __syncthreads();

  // ---- phase 2: QKV for own head; q,k -> registers, v -> vTL ----
  b16x8 qfv[4], kfv[4];
  #pragma unroll
  for (int s3 = 0; s3 < 3; ++s3) {
    b16x8 afr[2][6];
    float bv[2][4];
    #pragma unroll
    for (int hf = 0; hf < 2; ++hf) {
      const u32* wrow = wq + (size_t)(((h*3 + s3)*2 + hf)*16 + m) * 96;
      #pragma unroll
      for (int ks = 0; ks < 6; ++ks) afr[hf][ks] = ld_frag_g(wrow + ks*16 + qd*4);
      #pragma unroll
      for (int r = 0; r < 4; ++r) bv[hf][r] = qkvb[s3*192 + h*32 + qd*8 + hf*4 + r];
    }
    #pragma unroll
    for (int t = 0; t < 4; ++t) {
      f32x4 a0 = {0.f,0.f,0.f,0.f}, a1 = {0.f,0.f,0.f,0.f};
      #pragma unroll
      for (int ks = 0; ks < 6; ++ks) {
        b16x8 bfr = *(const b16x8*)(&rA.xl[(t*16 + m)*101 + ks*16 + qd*4]);
        a0 = __builtin_amdgcn_mfma_f32_16x16x32_bf16(afr[0][ks], bfr, a0, 0,0,0);
        a1 = __builtin_amdgcn_mfma_f32_16x16x32_bf16(afr[1][ks], bfr, a1, 0,0,0);
      }
      #pragma unroll
      for (int r = 0; r < 4; ++r) { a0[r] += bv[0][r]; a1[r] += bv[1][r]; }
      if (s3 < 2) {
        float ss = 0.f;
        #pragma unroll
        for (int r = 0; r < 4; ++r) ss = fmaf(a0[r],a0[r], fmaf(a1[r],a1[r], ss));
        ss += __shfl_xor(ss, 16);
        ss += __shfl_xor(ss, 32);
        float inv = 1.f / fmaxf(sqrtf(ss), 1e-12f);
        FragU tf;
        tf.u[0] = pack2(a0[0]*inv, a0[1]*inv);
        tf.u[1] = pack2(a0[2]*inv, a0[3]*inv);
        tf.u[2] = pack2(a1[0]*inv, a1[1]*inv);
        tf.u[3] = pack2(a1[2]*inv, a1[3]*inv);
        if (s3 == 0) qfv[t] = tf.s; else kfv[t] = tf.s;
      } else {
        float v8[8];
        #pragma unroll
        for (int r = 0; r < 4; ++r) { v8[r] = a0[r]; v8[4+r] = a1[r]; }
        #pragma unroll
        for (int e = 0; e < 8; ++e) {
          float pn = __shfl_xor(v8[e], 1);
          if ((m & 1) == 0) {
            int d = qd*8 + (e>>2)*4 + (e&3);
            rB.vTL[h][d*35 + t*8 + (m>>1)] = pack2(v8[e], pn);
          }
        }
      }
    }
  }
  __syncthreads();   // xl dead; vTL complete

  // ---- load V^T fragments into registers, then free vTL for aol ----
  b16x8 vfr[2][2];
  #pragma unroll
  for (int nt = 0; nt < 2; ++nt)
    #pragma unroll
    for (int ks = 0; ks < 2; ++ks)
      vfr[nt][ks] = *(const b16x8*)(&rB.vTL[h][(nt*16 + m)*35 + ks*16 + qd*4]);
  __syncthreads();   // vTL dead -> aol may be written; xl dead -> pbt may be written

  // ---- phase 3: attention (per-head wave), merged softmax+PV per q-tile ----
  const float sc = __expf(fminf(ls[h], 4.60517019f));
  const float* bmp = bm + ((size_t)(b & 63) * HEADS + h) * 4096;  // (col, row) layout
  u32* pbw = rA.pbt[h];
  #pragma unroll
  for (int mt = 0; mt < 4; ++mt) {
    f32x4 s4[4];
    #pragma unroll
    for (int ct = 0; ct < 4; ++ct) {
      f32x4 z = {0.f,0.f,0.f,0.f};
      s4[ct] = __builtin_amdgcn_mfma_f32_16x16x32_bf16(qfv[mt], kfv[ct], z, 0,0,0);
    }
    #pragma unroll
    for (int ct = 0; ct < 4; ++ct) {
      float4 b4 = *(const float4*)(bmp + (ct*16 + m)*64 + mt*16 + qd*4);
      s4[ct][0] = fmaf(s4[ct][0], sc, b4.x);
      s4[ct][1] = fmaf(s4[ct][1], sc, b4.y);
      s4[ct][2] = fmaf(s4[ct][2], sc, b4.z);
      s4[ct][3] = fmaf(s4[ct][3], sc, b4.w);
    }
    float rinv[4];
    #pragma unroll
    for (int r = 0; r < 4; ++r) {
      float mm = s4[0][r];
      #pragma unroll
      for (int ct = 1; ct < 4; ++ct) mm = fmaxf(mm, s4[ct][r]);
      mm = fmaxf(mm, __shfl_xor(mm, 1)); mm = fmaxf(mm, __shfl_xor(mm, 2));
      mm = fmaxf(mm, __shfl_xor(mm, 4)); mm = fmaxf(mm, __shfl_xor(mm, 8));
      float l = 0.f;
      #pragma unroll
      for (int ct = 0; ct < 4; ++ct) { s4[ct][r] = __expf(s4[ct][r] - mm); l += s4[ct][r]; }
      l += __shfl_xor(l, 1); l += __shfl_xor(l, 2);
      l += __shfl_xor(l, 4); l += __shfl_xor(l, 8);
      rinv[r] = 1.f / l;
      int rloc = qd*4 + r;
      #pragma unroll
      for (int ct = 0; ct < 4; ++ct) {
        float pv = s4[ct][r];
        float pn = __shfl_xor(pv, 1);
        if ((m & 1) == 0) pbw[rloc*35 + ct*8 + (m >> 1)] = pack2(pv, pn);
      }
    }
    b16x8 pa0 = *(const b16x8*)(&pbw[m*35 + qd*4]);
    b16x8 pa1 = *(const b16x8*)(&pbw[m*35 + 16 + qd*4]);
    #pragma unroll
    for (int nt = 0; nt < 2; ++nt) {
      f32x4 o = {0.f,0.f,0.f,0.f};
      o = __builtin_amdgcn_mfma_f32_16x16x32_bf16(pa0, vfr[nt][0], o, 0,0,0);
      o = __builtin_amdgcn_mfma_f32_16x16x32_bf16(pa1, vfr[nt][1], o, 0,0,0);
      #pragma unroll
      for (int r = 0; r < 4; ++r) {
        float val = o[r] * rinv[r];
        float pn = __shfl_xor(val, 1);
        if ((m & 1) == 0)
          rB.aol[(mt*16 + qd*4 + r)*99 + h*16 + nt*8 + (m >> 1)] = pack2(val, pn);
      }
    }
  }
  __syncthreads();

  // ---- phase 4: projection; wave wv handles output cols wv*32..wv*32+31 ----
  const int wv = h;
  b16x8 pfr[2][6];
  float pbv[2][4];
  #pragma unroll
  for (int jj = 0; jj < 2; ++jj) {
    const u32* wrow = wp + (size_t)((wv*2 + jj)*16 + m) * 96;
    #pragma unroll
    for (int ks = 0; ks < 6; ++ks) pfr[jj][ks] = ld_frag_g(wrow + ks*16 + qd*4);
    #pragma unroll
    for (int r = 0; r < 4; ++r) pbv[jj][r] = pb[(wv*2 + jj)*16 + qd*4 + r];
  }
  #pragma unroll 1
  for (int t = 0; t < 4; ++t) {
    f32x4 acc0 = {0.f,0.f,0.f,0.f}, acc1 = {0.f,0.f,0.f,0.f};
    #pragma unroll
    for (int ks = 0; ks < 6; ++ks) {
      b16x8 bfr = *(const b16x8*)(&rB.aol[(t*16 + m)*99 + ks*16 + qd*4]);
      acc0 = __builtin_amdgcn_mfma_f32_16x16x32_bf16(pfr[0][ks], bfr, acc0, 0,0,0);
      acc1 = __builtin_amdgcn_mfma_f32_16x16x32_bf16(pfr[1][ks], bfr, acc1, 0,0,0);
    }
    float* op = out + ((size_t)b*64 + t*16 + m) * DIM;
    *(float4*)(op + (wv*2+0)*16 + qd*4) =
        make_float4(acc0[0]+pbv[0][0], acc0[1]+pbv[0][1], acc0[2]+pbv[0][2], acc0[3]+pbv[0][3]);
    *(float4*)(op + (wv*2+1)*16 + qd*4) =
        make_float4(acc1[0]+pbv[1][0], acc1[1]+pbv[1][1], acc1[2]+pbv[1][2], acc1[3]+pbv[1][3]);
  }
}

extern "C" void kernel_launch(void* const* d_in, const int* in_sizes, int n_in,
                              void* d_out, int out_size, void* d_ws, size_t ws_size,
                              hipStream_t stream) {
  const float* x    = (const float*)d_in[0];
  const float* mask = (const float*)d_in[1];
  const float* rpb  = (const float*)d_in[2];
  const int*   ridx = (const int*)d_in[3];
  const float* w1   = (const float*)d_in[4];
  const float* b1   = (const float*)d_in[5];
  const float* w2   = (const float*)d_in[6];
  const float* qkvw = (const float*)d_in[7];
  const float* qkvb = (const float*)d_in[8];
  const float* pw   = (const float*)d_in[9];
  const float* pb   = (const float*)d_in[10];
  const float* ls   = (const float*)d_in[11];
  float* out = (float*)d_out;

  char* ws = (char*)d_ws;
  float* btab = (float*)(ws);                       // 16 KB slot
  float* bm   = (float*)(ws + 16384);               // 6,291,456 B
  u32* wq = (u32*)(ws + 16384 + 6291456);           // 221,184 B
  u32* wp = (u32*)(ws + 16384 + 6291456 + 221184);  // 73,728 B

  k_prep<<<376, 256, 0, stream>>>(rpb, w1, b1, w2, btab, qkvw, pw, wq, wp);
  k_bm<<<(NW * HEADS * 4096 + 255) / 256, 256, 0, stream>>>(btab, ridx, mask, bm);
  k_fused<<<BATCH, 384, 0, stream>>>(x, wq, qkvb, bm, ls, wp, pb, out);
}

// Round 6
// 408.850 us; speedup vs baseline: 1.4082x; 1.0908x over previous
//
#include <hip/hip_runtime.h>
#include <hip/hip_bf16.h>

#define DIM 192
#define HEADS 6
#define HD 32
#define NTOK 64
#define BATCH 2048
#define CPBH 512
#define TBL 343
#define NW 64

typedef unsigned int u32;
typedef __attribute__((ext_vector_type(8))) short b16x8;
typedef __attribute__((ext_vector_type(4))) float f32x4;

__device__ __forceinline__ unsigned short f2bf(float f) {
  union { __hip_bfloat16 h; unsigned short s; } cv;
  cv.h = __float2bfloat16(f);
  return cv.s;
}
__device__ __forceinline__ u32 pack2(float a, float b) {
  return (u32)f2bf(a) | ((u32)f2bf(b) << 16);
}
union FragU { u32 u[4]; b16x8 s; uint4 q; };

__device__ __forceinline__ b16x8 ld_frag_g(const u32* p) {
  FragU f; f.q = *(const uint4*)p; return f.s;
}
__device__ __forceinline__ u32 shf(u32 v, int l) {
  return (u32)__shfl((int)v, l);
}

// ---------- merged prep: CPB MLP (blocks 0..87) + weight cvt (blocks 88..375) ----------
__global__ __launch_bounds__(256) void k_prep(
    const float* __restrict__ rpb, const float* __restrict__ w1,
    const float* __restrict__ b1, const float* __restrict__ w2,
    float* __restrict__ tab,
    const float* __restrict__ qkvw, const float* __restrict__ pw,
    u32* __restrict__ wq, u32* __restrict__ wp) {
  const int tid = threadIdx.x;
  if (blockIdx.x < 88) {
    int t = blockIdx.x * 4 + (tid >> 6);
    int lane = tid & 63;
    if (t >= TBL) return;
    float r0 = rpb[t*3], r1 = rpb[t*3+1], r2 = rpb[t*3+2];
    float a[HEADS];
    #pragma unroll
    for (int h = 0; h < HEADS; ++h) a[h] = 0.f;
    #pragma unroll
    for (int kk = 0; kk < 8; ++kk) {
      int k = lane * 8 + kk;
      float hv = fmaf(r0, w1[k*3], fmaf(r1, w1[k*3+1], fmaf(r2, w1[k*3+2], b1[k])));
      hv = fmaxf(hv, 0.f);
      #pragma unroll
      for (int h = 0; h < HEADS; ++h) a[h] = fmaf(hv, w2[h*CPBH + k], a[h]);
    }
    #pragma unroll
    for (int h = 0; h < HEADS; ++h) {
      a[h] += __shfl_xor(a[h], 1);  a[h] += __shfl_xor(a[h], 2);
      a[h] += __shfl_xor(a[h], 4);  a[h] += __shfl_xor(a[h], 8);
      a[h] += __shfl_xor(a[h], 16); a[h] += __shfl_xor(a[h], 32);
    }
    if (lane == 0) {
      #pragma unroll
      for (int h = 0; h < HEADS; ++h) tab[t*HEADS + h] = a[h];
    }
    return;
  }
  // weight conversion; qkv rows permuted so MFMA output layout == attention frag layout
  int i = (blockIdx.x - 88) * 256 + tid;
  if (i < 55296) {
    int R = i / 96, c = i % 96;
    int h  = R / 96;
    int t  = R - h * 96;
    int s3 = t >> 5;
    int u  = t & 31;
    int hf = (u >> 4) & 1;
    int p  = u & 15;
    int d  = ((p >> 2) << 3) + (hf << 2) + (p & 3);
    int orig = s3 * 192 + h * 32 + d;
    wq[i] = pack2(qkvw[orig*192 + 2*c], qkvw[orig*192 + 2*c + 1]);
  } else if (i < 55296 + 18432) {
    int j = i - 55296;
    wp[j] = pack2(pw[2*j], pw[2*j+1]);
  }
}

// ---------- bias+mask table, ROW-major: (nW, H, row, col) fp32 ----------
__global__ void k_bm(const float* __restrict__ tab, const int* __restrict__ ridx,
                     const float* __restrict__ mask, float* __restrict__ bm) {
  int idx = blockIdx.x * blockDim.x + threadIdx.x;
  if (idx >= NW * HEADS * 4096) return;
  int ij = idx & 4095;
  int h = (idx >> 12) % HEADS;
  int nw = idx / (HEADS * 4096);
  float v = tab[ridx[ij] * HEADS + h];
  bm[idx] = 16.f / (1.f + __expf(-v)) + mask[nw * 4096 + ij];
}

// ---------- fully fused: QKV + cosine attention + projection ----------
// Target: VGPR <= 64 (gfx950 granule: <=64 -> 8 waves/SIMD -> 3 blocks/CU at 52.7KB LDS).
// Swapped QK^T (S^T) + in-register P transpose. NOTE: the transpose shuffles are
// hoisted OUT of the lowq ternary — __shfl under a divergent branch pulls from
// inactive lanes (undefined) which was R4's correctness failure.
union RegA { u32 xl[NTOK * 101]; u32 aol[NTOK * 99]; };

__global__ __launch_bounds__(384, 8) void k_fused(
    const float* __restrict__ x, const u32* __restrict__ wq,
    const float* __restrict__ qkvb, const float* __restrict__ bm,
    const float* __restrict__ ls, const u32* __restrict__ wp,
    const float* __restrict__ pb, float* __restrict__ out) {
  __shared__ RegA rA;                   // 25,856 B  xl (ph1-2) / aol (ph3-4)
  __shared__ u32 vTL[HEADS][32 * 35];   // 26,880 B  V^T per head (ph2 -> ph3)

  const int tid = threadIdx.x;
  const int b = blockIdx.x;
  const int h = tid >> 6;               // wave = head
  const int lane = tid & 63;
  const int m = lane & 15, qd = lane >> 4;

  // ---- phase 1: stage x as bf16 ----
  {
    const float4* xg = (const float4*)(x + (size_t)b * (NTOK * DIM));
    for (int i = tid; i < (NTOK * DIM) / 4; i += 384) {
      float4 v = xg[i];
      int flat = i * 4, tok = flat / DIM, k = flat % DIM;
      rA.xl[tok*101 + k/2]     = pack2(v.x, v.y);
      rA.xl[tok*101 + k/2 + 1] = pack2(v.z, v.w);
    }
  }
  __syncthreads();

  // ---- phase 2: QKV for own head; q,k -> registers, v -> vTL ----
  b16x8 qk[2][4];   // [0]=q frags, [1]=k frags
  #pragma unroll
  for (int s3 = 0; s3 < 2; ++s3) {
    float bv0[4], bv1[4];
    #pragma unroll
    for (int r = 0; r < 4; ++r) {
      bv0[r] = qkvb[s3*192 + h*32 + qd*8 + r];
      bv1[r] = qkvb[s3*192 + h*32 + qd*8 + 4 + r];
    }
    const u32* w0 = wq + (size_t)(((h*3 + s3)*2 + 0)*16 + m) * 96;
    const u32* w1 = wq + (size_t)(((h*3 + s3)*2 + 1)*16 + m) * 96;
    #pragma unroll
    for (int tp = 0; tp < 2; ++tp) {
      f32x4 ac[2][2];
      #pragma unroll
      for (int tt = 0; tt < 2; ++tt) {
        ac[tt][0] = (f32x4){0.f,0.f,0.f,0.f};
        ac[tt][1] = (f32x4){0.f,0.f,0.f,0.f};
      }
      #pragma unroll 1
      for (int ks = 0; ks < 6; ++ks) {
        b16x8 a0f = ld_frag_g(w0 + ks*16 + qd*4);
        b16x8 a1f = ld_frag_g(w1 + ks*16 + qd*4);
        #pragma unroll
        for (int tt = 0; tt < 2; ++tt) {
          b16x8 bfr = *(const b16x8*)(&rA.xl[((tp*2+tt)*16 + m)*101 + ks*16 + qd*4]);
          ac[tt][0] = __builtin_amdgcn_mfma_f32_16x16x32_bf16(a0f, bfr, ac[tt][0], 0,0,0);
          ac[tt][1] = __builtin_amdgcn_mfma_f32_16x16x32_bf16(a1f, bfr, ac[tt][1], 0,0,0);
        }
      }
      #pragma unroll
      for (int tt = 0; tt < 2; ++tt) {
        f32x4 a0 = ac[tt][0], a1 = ac[tt][1];
        #pragma unroll
        for (int r = 0; r < 4; ++r) { a0[r] += bv0[r]; a1[r] += bv1[r]; }
        float ss = 0.f;
        #pragma unroll
        for (int r = 0; r < 4; ++r) ss = fmaf(a0[r],a0[r], fmaf(a1[r],a1[r], ss));
        ss += __shfl_xor(ss, 16);
        ss += __shfl_xor(ss, 32);
        float inv = 1.f / fmaxf(sqrtf(ss), 1e-12f);
        FragU tf;
        tf.u[0] = pack2(a0[0]*inv, a0[1]*inv);
        tf.u[1] = pack2(a0[2]*inv, a0[3]*inv);
        tf.u[2] = pack2(a1[0]*inv, a1[1]*inv);
        tf.u[3] = pack2(a1[2]*inv, a1[3]*inv);
        qk[s3][tp*2 + tt] = tf.s;
      }
    }
  }
  // V: per-tile pass
  {
    float bv0[4], bv1[4];
    #pragma unroll
    for (int r = 0; r < 4; ++r) {
      bv0[r] = qkvb[2*192 + h*32 + qd*8 + r];
      bv1[r] = qkvb[2*192 + h*32 + qd*8 + 4 + r];
    }
    const u32* w0 = wq + (size_t)(((h*3 + 2)*2 + 0)*16 + m) * 96;
    const u32* w1 = wq + (size_t)(((h*3 + 2)*2 + 1)*16 + m) * 96;
    #pragma unroll 1
    for (int t = 0; t < 4; ++t) {
      f32x4 a0 = (f32x4){0.f,0.f,0.f,0.f}, a1 = (f32x4){0.f,0.f,0.f,0.f};
      #pragma unroll 1
      for (int ks = 0; ks < 6; ++ks) {
        b16x8 a0f = ld_frag_g(w0 + ks*16 + qd*4);
        b16x8 a1f = ld_frag_g(w1 + ks*16 + qd*4);
        b16x8 bfr = *(const b16x8*)(&rA.xl[(t*16 + m)*101 + ks*16 + qd*4]);
        a0 = __builtin_amdgcn_mfma_f32_16x16x32_bf16(a0f, bfr, a0, 0,0,0);
        a1 = __builtin_amdgcn_mfma_f32_16x16x32_bf16(a1f, bfr, a1, 0,0,0);
      }
      float v8[8];
      #pragma unroll
      for (int r = 0; r < 4; ++r) { v8[r] = a0[r] + bv0[r]; v8[4+r] = a1[r] + bv1[r]; }
      #pragma unroll
      for (int e = 0; e < 8; ++e) {
        float pn = __shfl_xor(v8[e], 1);
        if ((m & 1) == 0) {
          int d = qd*8 + (e>>2)*4 + (e&3);
          vTL[h][d*35 + t*8 + (m>>1)] = pack2(v8[e], pn);
        }
      }
    }
  }
  __syncthreads();   // xl dead (aol may be written); vTL complete

  // ---- phase 3: swapped attention. S^T = mfma(k, q):
  // lane(m,qd) holds S[q = mt*16+m][k = ct*16+qd*4+r] in s4[ct][r].
  const float sc = __expf(fminf(ls[h], 4.60517019f));
  const float* bmp = bm + ((size_t)(b & 63) * HEADS + h) * 4096;  // row-major (q, k)
  const int L0 = (((qd*2) & 3) << 4) + m;
  const int L1 = (((qd*2 + 1) & 3) << 4) + m;
  const bool lowq = (qd < 2);
  #pragma unroll
  for (int mt = 0; mt < 4; ++mt) {
    f32x4 s4[4];
    #pragma unroll
    for (int ct = 0; ct < 4; ++ct) {
      f32x4 z = {0.f,0.f,0.f,0.f};
      s4[ct] = __builtin_amdgcn_mfma_f32_16x16x32_bf16(qk[1][ct], qk[0][mt], z, 0,0,0);
    }
    #pragma unroll
    for (int ct = 0; ct < 4; ++ct) {
      float4 b4 = *(const float4*)(bmp + (mt*16 + m)*64 + ct*16 + qd*4);
      s4[ct][0] = fmaf(s4[ct][0], sc, b4.x);
      s4[ct][1] = fmaf(s4[ct][1], sc, b4.y);
      s4[ct][2] = fmaf(s4[ct][2], sc, b4.z);
      s4[ct][3] = fmaf(s4[ct][3], sc, b4.w);
    }
    float mm = s4[0][0];
    #pragma unroll
    for (int ct = 0; ct < 4; ++ct)
      #pragma unroll
      for (int r = 0; r < 4; ++r) mm = fmaxf(mm, s4[ct][r]);
    mm = fmaxf(mm, __shfl_xor(mm, 16));
    mm = fmaxf(mm, __shfl_xor(mm, 32));
    float l = 0.f;
    #pragma unroll
    for (int ct = 0; ct < 4; ++ct)
      #pragma unroll
      for (int r = 0; r < 4; ++r) { s4[ct][r] = __expf(s4[ct][r] - mm); l += s4[ct][r]; }
    l += __shfl_xor(l, 16);
    l += __shfl_xor(l, 32);
    float rinv = 1.f / l;
    // pack P pairs
    u32 pk0a = pack2(s4[0][0], s4[0][1]), pk0b = pack2(s4[0][2], s4[0][3]);
    u32 pk1a = pack2(s4[1][0], s4[1][1]), pk1b = pack2(s4[1][2], s4[1][3]);
    u32 pk2a = pack2(s4[2][0], s4[2][1]), pk2b = pack2(s4[2][2], s4[2][3]);
    u32 pk3a = pack2(s4[3][0], s4[3][1]), pk3b = pack2(s4[3][2], s4[3][3]);
    // in-register transpose: ALL shuffles execute with full EXEC (convergent),
    // the lowq selection happens on already-shuffled values (v_cndmask).
    FragU pa0, pa1;
    { u32 t0 = shf(pk0a, L0), t1 = shf(pk1a, L0); pa0.u[0] = lowq ? t0 : t1; }
    { u32 t0 = shf(pk0b, L0), t1 = shf(pk1b, L0); pa0.u[1] = lowq ? t0 : t1; }
    { u32 t0 = shf(pk0a, L1), t1 = shf(pk1a, L1); pa0.u[2] = lowq ? t0 : t1; }
    { u32 t0 = shf(pk0b, L1), t1 = shf(pk1b, L1); pa0.u[3] = lowq ? t0 : t1; }
    { u32 t0 = shf(pk2a, L0), t1 = shf(pk3a, L0); pa1.u[0] = lowq ? t0 : t1; }
    { u32 t0 = shf(pk2b, L0), t1 = shf(pk3b, L0); pa1.u[1] = lowq ? t0 : t1; }
    { u32 t0 = shf(pk2a, L1), t1 = shf(pk3a, L1); pa1.u[2] = lowq ? t0 : t1; }
    { u32 t0 = shf(pk2b, L1), t1 = shf(pk3b, L1); pa1.u[3] = lowq ? t0 : t1; }
    // rinv for PV-out rows qd*4+r (uniform across qd after xor16/32)
    float rv[4];
    #pragma unroll
    for (int r = 0; r < 4; ++r) rv[r] = __shfl(rinv, qd*4 + r);
    // PV: V^T frags re-read from LDS per nt
    #pragma unroll
    for (int nt = 0; nt < 2; ++nt) {
      b16x8 vf0 = *(const b16x8*)(&vTL[h][(nt*16 + m)*35 + qd*4]);
      b16x8 vf1 = *(const b16x8*)(&vTL[h][(nt*16 + m)*35 + 16 + qd*4]);
      f32x4 o = {0.f,0.f,0.f,0.f};
      o = __builtin_amdgcn_mfma_f32_16x16x32_bf16(pa0.s, vf0, o, 0,0,0);
      o = __builtin_amdgcn_mfma_f32_16x16x32_bf16(pa1.s, vf1, o, 0,0,0);
      #pragma unroll
      for (int r = 0; r < 4; ++r) {
        float val = o[r] * rv[r];
        float pn = __shfl_xor(val, 1);
        if ((m & 1) == 0)
          rA.aol[(mt*16 + qd*4 + r)*99 + h*16 + nt*8 + (m >> 1)] = pack2(val, pn);
      }
    }
  }
  __syncthreads();

  // ---- phase 4: projection, ks-outer single weight pass ----
  float pbv0[4], pbv1[4];
  #pragma unroll
  for (int r = 0; r < 4; ++r) {
    pbv0[r] = pb[(h*2 + 0)*16 + qd*4 + r];
    pbv1[r] = pb[(h*2 + 1)*16 + qd*4 + r];
  }
  const u32* p0 = wp + (size_t)((h*2 + 0)*16 + m) * 96;
  const u32* p1 = wp + (size_t)((h*2 + 1)*16 + m) * 96;
  f32x4 pacc[4][2];
  #pragma unroll
  for (int t = 0; t < 4; ++t) {
    pacc[t][0] = (f32x4){0.f,0.f,0.f,0.f};
    pacc[t][1] = (f32x4){0.f,0.f,0.f,0.f};
  }
  #pragma unroll 1
  for (int ks = 0; ks < 6; ++ks) {
    b16x8 pf0 = ld_frag_g(p0 + ks*16 + qd*4);
    b16x8 pf1 = ld_frag_g(p1 + ks*16 + qd*4);
    #pragma unroll
    for (int t = 0; t < 4; ++t) {
      b16x8 bfr = *(const b16x8*)(&rA.aol[(t*16 + m)*99 + ks*16 + qd*4]);
      pacc[t][0] = __builtin_amdgcn_mfma_f32_16x16x32_bf16(pf0, bfr, pacc[t][0], 0,0,0);
      pacc[t][1] = __builtin_amdgcn_mfma_f32_16x16x32_bf16(pf1, bfr, pacc[t][1], 0,0,0);
    }
  }
  #pragma unroll
  for (int t = 0; t < 4; ++t) {
    float* op = out + ((size_t)b*64 + t*16 + m) * DIM;
    *(float4*)(op + (h*2+0)*16 + qd*4) =
        make_float4(pacc[t][0][0]+pbv0[0], pacc[t][0][1]+pbv0[1],
                    pacc[t][0][2]+pbv0[2], pacc[t][0][3]+pbv0[3]);
    *(float4*)(op + (h*2+1)*16 + qd*4) =
        make_float4(pacc[t][1][0]+pbv1[0], pacc[t][1][1]+pbv1[1],
                    pacc[t][1][2]+pbv1[2], pacc[t][1][3]+pbv1[3]);
  }
}

extern "C" void kernel_launch(void* const* d_in, const int* in_sizes, int n_in,
                              void* d_out, int out_size, void* d_ws, size_t ws_size,
                              hipStream_t stream) {
  const float* x    = (const float*)d_in[0];
  const float* mask = (const float*)d_in[1];
  const float* rpb  = (const float*)d_in[2];
  const int*   ridx = (const int*)d_in[3];
  const float* w1   = (const float*)d_in[4];
  const float* b1   = (const float*)d_in[5];
  const float* w2   = (const float*)d_in[6];
  const float* qkvw = (const float*)d_in[7];
  const float* qkvb = (const float*)d_in[8];
  const float* pw   = (const float*)d_in[9];
  const float* pb   = (const float*)d_in[10];
  const float* ls   = (const float*)d_in[11];
  float* out = (float*)d_out;

  char* ws = (char*)d_ws;
  float* btab = (float*)(ws);                       // 16 KB slot
  float* bm   = (float*)(ws + 16384);               // 6,291,456 B
  u32* wq = (u32*)(ws + 16384 + 6291456);           // 221,184 B
  u32* wp = (u32*)(ws + 16384 + 6291456 + 221184);  // 73,728 B

  k_prep<<<376, 256, 0, stream>>>(rpb, w1, b1, w2, btab, qkvw, pw, wq, wp);
  k_bm<<<(NW * HEADS * 4096 + 255) / 256, 256, 0, stream>>>(btab, ridx, mask, bm);
  k_fused<<<BATCH, 384, 0, stream>>>(x, wq, qkvb, bm, ls, wp, pb, out);
}